// Round 6
// baseline (2196.394 us; speedup 1.0000x reference)
//
#include <hip/hip_runtime.h>
#include <hip/hip_bf16.h>

typedef __bf16 bf16x8 __attribute__((ext_vector_type(8)));
typedef float f32x4 __attribute__((ext_vector_type(4)));

static constexpr int NT = 32768;  // S*B tokens
static constexpr int D_ = 512;
static constexpr int D3 = 1536;
static constexpr int DF = 2048;
static constexpr int L_ = 6;

#define AS1 __attribute__((address_space(1)))
#define AS3 __attribute__((address_space(3)))

__device__ __forceinline__ void gload_lds16(const void* g, void* l) {
  __builtin_amdgcn_global_load_lds((const AS1 void*)g, (AS3 void*)l, 16, 0, 0);
}

// ============ persistent 256x256 8-phase GEMM: C = A*W^T + bias ============
// 8 waves (2M x 4N), per-wave 128x64 output. Each block processes TPB output
// tiles through ONE continuously-running 8-phase pipeline over a flat K-slot
// sequence (slot s -> tile s>>LNK, kt s&(NKT-1)); tile boundaries align to
// iteration boundaries. Ledger identical to the verified round-5 schedule:
//   P1: buf1.A <- slot s1 (current tile)      P2/P3: buf0.B <- slot s0+2
//   P4: vmcnt(4)                              P5/P6: buf0.A <- slot s0+2
//   P7/P8: buf1.B <- slot s1+2                P8: vmcnt(4)
// (vmcnt(0) on the final iteration). At tile end, acc drains via the
// then-dead buf1.A regions (4KB/wave scratch, 4 passes of 32 rows) into
// coalesced uint4 stores; one barrier then protects the scratch before P1
// restages it.
template<int K, int NTN, int TPB, bool RELU>
__global__ __launch_bounds__(512, 2) void gemm256(
    const __hip_bfloat16* __restrict__ A,
    const __hip_bfloat16* __restrict__ W,
    const float* __restrict__ bias,
    __hip_bfloat16* __restrict__ Cout) {
  __shared__ __align__(16) char lds[131072];
  const int t = threadIdx.x;
  const int l = t & 63, w = t >> 6;
  const int lrow = l & 15, lhi = l >> 4;
  const int wr = w >> 2, wc = w & 3;

  const int lin = blockIdx.x;
  const int wg = (lin & 7) * ((int)gridDim.x >> 3) + (lin >> 3);
  const int T0 = wg * TPB;  // first output tile; tile g: m=g/NTN, n=g%NTN

  constexpr int NKT = K / 64;
  constexpr int LNK = (NKT == 8) ? 3 : 5;
  constexpr int NITT = TPB * NKT / 2;
  constexpr int N = NTN * 256;

  const int srow = t >> 3;
  const int sun = t & 7;

  auto stage = [&](int buf, int reg, const __hip_bfloat16* P, int rowbase, int kt) {
    const int kb = kt * 64;
    char* dst = lds + (buf * 4 + reg) * 16384 + w * 1024;
#pragma unroll
    for (int pass = 0; pass < 2; ++pass) {
      int rl = pass * 64 + srow;
      int u = sun ^ (rl & 7);
      gload_lds16(P + (size_t)(rowbase + rl) * K + kb + u * 8, dst + pass * 8192);
    }
  };
  auto rdA = [&](int buf, int m, int ks) -> bf16x8 {
    int r = m * 16 + lrow;
    return *(const bf16x8*)(lds + (buf * 4 + wr) * 16384 + r * 128 +
                            (((ks * 4 + lhi) ^ (r & 7)) << 4));
  };
  auto rdB = [&](int buf, int n, int ks) -> bf16x8 {
    int r = (wc & 1) * 64 + n * 16 + lrow;
    return *(const bf16x8*)(lds + (buf * 4 + 2 + (wc >> 1)) * 16384 + r * 128 +
                            (((ks * 4 + lhi) ^ (r & 7)) << 4));
  };

  f32x4 acc[8][4] = {};
  bf16x8 bfrag[4][2], afrag[2][2];

  // per-tile epilogue through buf1.A regions (dead at tile boundary)
  auto epi = [&](int g) {
    const int tm = (g / NTN) * 256, tn = (g % NTN) * 256;
    char* ep = lds + 65536 + w * 4096;  // regions 4,5: 8 waves x 4KB
    const int er = l >> 3, ec = l & 7;
#pragma unroll
    for (int p = 0; p < 4; ++p) {
#pragma unroll
      for (int n = 0; n < 4; ++n) {
        float bv = bias[tn + wc * 64 + n * 16 + lrow];
#pragma unroll
        for (int mm = 0; mm < 2; ++mm) {
#pragma unroll
          for (int j = 0; j < 4; ++j) {
            float v = acc[2 * p + mm][n][j] + bv;
            if (RELU) v = fmaxf(v, 0.f);
            int rl = mm * 16 + lhi * 4 + j;
            int col = n * 16 + lrow;
            *(__hip_bfloat16*)(ep + rl * 128 + (((col >> 3) ^ (rl & 7)) << 4) +
                               (col & 7) * 2) = __float2bfloat16(v);
          }
        }
      }
      asm volatile("s_waitcnt lgkmcnt(0)" ::: "memory");
      __builtin_amdgcn_sched_barrier(0);
#pragma unroll
      for (int q = 0; q < 4; ++q) {
        int rl = q * 8 + er;
        uint4 vv = *(const uint4*)(ep + rl * 128 + ((ec ^ (rl & 7)) << 4));
        *(uint4*)&Cout[(size_t)(tm + wr * 128 + p * 32 + rl) * N + tn + wc * 64 +
                       ec * 8] = vv;
      }
      asm volatile("s_waitcnt lgkmcnt(0)" ::: "memory");
      __builtin_amdgcn_sched_barrier(0);
    }
  };

  // ---- prologue: tile T0 slots 0 (A+B) and 1 (B); force slot0 landed
  {
    const int mb = (T0 / NTN) * 256, nb = (T0 % NTN) * 256;
    stage(0, 2, W, nb, 0);
    stage(0, 3, W, nb + 128, 0);
    stage(0, 0, A, mb, 0);
    stage(0, 1, A, mb + 128, 0);
    stage(1, 2, W, nb, 1);
    stage(1, 3, W, nb + 128, 1);
  }
  asm volatile("s_waitcnt vmcnt(4)" ::: "memory");
  __builtin_amdgcn_s_barrier();

#define GPHASE(BUF, MB, RB, STG, VMS)                                       \
  {                                                                          \
    if (RB) {                                                                \
      _Pragma("unroll") for (int n = 0; n < 4; ++n)                          \
          _Pragma("unroll") for (int ks = 0; ks < 2; ++ks)                   \
              bfrag[n][ks] = rdB(BUF, n, ks);                                \
    }                                                                        \
    _Pragma("unroll") for (int ks = 0; ks < 2; ++ks) {                       \
      afrag[0][ks] = rdA(BUF, MB, ks);                                       \
      afrag[1][ks] = rdA(BUF, MB + 1, ks);                                   \
    }                                                                        \
    STG;                                                                     \
    VMS;                                                                     \
    __builtin_amdgcn_sched_barrier(0);                                       \
    __builtin_amdgcn_s_barrier();                                            \
    asm volatile("s_waitcnt lgkmcnt(0)" ::: "memory");                       \
    __builtin_amdgcn_sched_barrier(0);                                       \
    __builtin_amdgcn_s_setprio(1);                                           \
    _Pragma("unroll") for (int n = 0; n < 4; ++n)                            \
        _Pragma("unroll") for (int ks = 0; ks < 2; ++ks) {                   \
      acc[MB][n] = __builtin_amdgcn_mfma_f32_16x16x32_bf16(                  \
          afrag[0][ks], bfrag[n][ks], acc[MB][n], 0, 0, 0);                  \
      acc[MB + 1][n] = __builtin_amdgcn_mfma_f32_16x16x32_bf16(              \
          afrag[1][ks], bfrag[n][ks], acc[MB + 1][n], 0, 0, 0);              \
    }                                                                        \
    __builtin_amdgcn_s_setprio(0);                                           \
    __builtin_amdgcn_sched_barrier(0);                                       \
    __builtin_amdgcn_s_barrier();                                            \
  }

#define VM_CNT                                              \
  if (more) {                                               \
    asm volatile("s_waitcnt vmcnt(4)" ::: "memory");        \
  } else {                                                  \
    asm volatile("s_waitcnt vmcnt(0)" ::: "memory");        \
  }

  for (int it = 0; it < NITT; ++it) {
    const bool more = (it + 1 < NITT);
    const int gc = T0 + (it >> (LNK - 1));           // current tile
    const int kt1 = (2 * it + 1) & (NKT - 1);
    const int sn0 = 2 * it + 2, sn1 = 2 * it + 3;    // lookahead slots
    const int gn0 = T0 + (sn0 >> LNK), ktn0 = sn0 & (NKT - 1);
    const int gn1 = T0 + (sn1 >> LNK), ktn1 = sn1 & (NKT - 1);
    const int mc = (gc / NTN) * 256;
    const int m0 = (gn0 / NTN) * 256, n0b = (gn0 % NTN) * 256;
    const int n1b = (gn1 % NTN) * 256;

    // K-tile s0 from buf0
    GPHASE(0, 0, 1, { stage(1, 0, A, mc, kt1); stage(1, 1, A, mc + 128, kt1); }, );
    GPHASE(0, 2, 0, { if (more) stage(0, 2, W, n0b, ktn0); }, );
    GPHASE(0, 4, 0, { if (more) stage(0, 3, W, n0b + 128, ktn0); }, );
    GPHASE(0, 6, 0, , VM_CNT);
    // K-tile s1 from buf1
    GPHASE(1, 0, 1, { if (more) stage(0, 0, A, m0, ktn0); }, );
    GPHASE(1, 2, 0, { if (more) stage(0, 1, A, m0 + 128, ktn0); }, );
    GPHASE(1, 4, 0, { if (more) stage(1, 2, W, n1b, ktn1); }, );
    GPHASE(1, 6, 0, { if (more) stage(1, 3, W, n1b + 128, ktn1); }, VM_CNT);

    if (((it + 1) & ((NKT >> 1) - 1)) == 0) {  // tile gc finished
      epi(gc);
      f32x4 z = 0.f;
#pragma unroll
      for (int m = 0; m < 8; ++m)
#pragma unroll
        for (int n = 0; n < 4; ++n) acc[m][n] = z;
      __builtin_amdgcn_s_barrier();  // scratch reads done before P1 restages
    }
  }
#undef GPHASE
#undef VM_CNT
}

// ---------------- Windowed attention: one wave per (window, b, h) --------
// qkv: [CT, 1536] bf16 (q pre-scaled by 1/8 via weight folding). o: [CT,512].
__global__ __launch_bounds__(128) void attn_win(
    const __hip_bfloat16* __restrict__ qkv, __hip_bfloat16* __restrict__ o) {
  __shared__ __align__(16) char lds[2 * 18432];
  const int t = threadIdx.x, l = t & 63, w = t >> 6;
  char* vt = lds + w * 18432;          // Vt[d][k], stride 72 bf16
  char* pl = vt + 9216;                // P[q][k],  stride 72 bf16
  const int wid = blockIdx.x * 2 + w;
  const int h = wid & 7, b = (wid >> 3) & 3, nw = wid >> 5;
  const int lrow = l & 15, lhi = l >> 4;
  const __hip_bfloat16* qp = qkv + (size_t)(nw * 256 + b) * 1536 + h * 64;
  const __hip_bfloat16* kp = qp + 512;
  const __hip_bfloat16* vp = qp + 1024;

  // stage V transposed into LDS
  {
    const int d0 = (l & 7) * 8;
    const int r0 = l >> 3;
#pragma unroll
    for (int i = 0; i < 8; ++i) {
      int r = r0 + i * 8;
      union { uint4 u; __hip_bfloat16 e[8]; } vv;
      vv.u = *(const uint4*)(vp + (size_t)r * 6144 + d0);
#pragma unroll
      for (int j = 0; j < 8; ++j)
        *(__hip_bfloat16*)(vt + ((d0 + j) * 72 + r) * 2) = vv.e[j];
    }
  }

  // Q/K fragments straight from global
  bf16x8 qf[4][2], kf[4][2];
#pragma unroll
  for (int mi = 0; mi < 4; ++mi)
#pragma unroll
    for (int ks = 0; ks < 2; ++ks) {
      int r = mi * 16 + lrow;
      int d = ks * 32 + lhi * 8;
      qf[mi][ks] = __builtin_bit_cast(bf16x8, *(const uint4*)(qp + (size_t)r * 6144 + d));
      kf[mi][ks] = __builtin_bit_cast(bf16x8, *(const uint4*)(kp + (size_t)r * 6144 + d));
    }

  // S = Q K^T  (64x64)
  f32x4 s[4][4] = {};
#pragma unroll
  for (int mi = 0; mi < 4; ++mi)
#pragma unroll
    for (int ni = 0; ni < 4; ++ni) {
      s[mi][ni] = __builtin_amdgcn_mfma_f32_16x16x32_bf16(qf[mi][0], kf[ni][0], s[mi][ni], 0, 0, 0);
      s[mi][ni] = __builtin_amdgcn_mfma_f32_16x16x32_bf16(qf[mi][1], kf[ni][1], s[mi][ni], 0, 0, 0);
    }

  // softmax over k (cols)
#pragma unroll
  for (int mi = 0; mi < 4; ++mi)
#pragma unroll
    for (int j = 0; j < 4; ++j) {
      float mx = s[mi][0][j];
#pragma unroll
      for (int ni = 1; ni < 4; ++ni) mx = fmaxf(mx, s[mi][ni][j]);
      mx = fmaxf(mx, __shfl_xor(mx, 1));
      mx = fmaxf(mx, __shfl_xor(mx, 2));
      mx = fmaxf(mx, __shfl_xor(mx, 4));
      mx = fmaxf(mx, __shfl_xor(mx, 8));
      float p[4], sum = 0.f;
#pragma unroll
      for (int ni = 0; ni < 4; ++ni) { p[ni] = __expf(s[mi][ni][j] - mx); sum += p[ni]; }
      sum += __shfl_xor(sum, 1);
      sum += __shfl_xor(sum, 2);
      sum += __shfl_xor(sum, 4);
      sum += __shfl_xor(sum, 8);
      float inv = 1.f / sum;
      int row = mi * 16 + lhi * 4 + j;
#pragma unroll
      for (int ni = 0; ni < 4; ++ni)
        *(__hip_bfloat16*)(pl + (row * 72 + ni * 16 + lrow) * 2) =
            __float2bfloat16(p[ni] * inv);
    }

  // O = P V
  bf16x8 pf[4][2], vf[4][2];
#pragma unroll
  for (int mi = 0; mi < 4; ++mi)
#pragma unroll
    for (int ks = 0; ks < 2; ++ks)
      pf[mi][ks] = *(const bf16x8*)(pl + ((mi * 16 + lrow) * 72 + ks * 32 + lhi * 8) * 2);
#pragma unroll
  for (int ni = 0; ni < 4; ++ni)
#pragma unroll
    for (int ks = 0; ks < 2; ++ks)
      vf[ni][ks] = *(const bf16x8*)(vt + ((ni * 16 + lrow) * 72 + ks * 32 + lhi * 8) * 2);

  f32x4 acc[4][4] = {};
#pragma unroll
  for (int mi = 0; mi < 4; ++mi)
#pragma unroll
    for (int ni = 0; ni < 4; ++ni) {
      acc[mi][ni] = __builtin_amdgcn_mfma_f32_16x16x32_bf16(pf[mi][0], vf[ni][0], acc[mi][ni], 0, 0, 0);
      acc[mi][ni] = __builtin_amdgcn_mfma_f32_16x16x32_bf16(pf[mi][1], vf[ni][1], acc[mi][ni], 0, 0, 0);
    }

  __hip_bfloat16* op = o + (size_t)(nw * 256 + b) * 512 + h * 64;
#pragma unroll
  for (int mi = 0; mi < 4; ++mi)
#pragma unroll
    for (int ni = 0; ni < 4; ++ni) {
      int col = ni * 16 + lrow;
#pragma unroll
      for (int j = 0; j < 4; ++j) {
        int row = mi * 16 + lhi * 4 + j;
        op[(size_t)row * 2048 + col] = __float2bfloat16(acc[mi][ni][j]);
      }
    }
}

// ---------------- residual + LayerNorm (wave per row of 512) -------------
__global__ __launch_bounds__(256) void ln_res(
    float* __restrict__ x, const __hip_bfloat16* __restrict__ f,
    const float* __restrict__ g, const float* __restrict__ be,
    __hip_bfloat16* __restrict__ xb) {
  const int w = threadIdx.x >> 6, l = threadIdx.x & 63;
  const size_t row = (size_t)blockIdx.x * 4 + w;
  float* xr = x + row * 512;
  const int c = l * 8;
  float4 a0 = *(const float4*)(xr + c);
  float4 a1 = *(const float4*)(xr + c + 4);
  union { uint4 u; __hip_bfloat16 e[8]; } fb;
  fb.u = *(const uint4*)(f + row * 512 + c);
  float v[8] = {a0.x + __bfloat162float(fb.e[0]), a0.y + __bfloat162float(fb.e[1]),
                a0.z + __bfloat162float(fb.e[2]), a0.w + __bfloat162float(fb.e[3]),
                a1.x + __bfloat162float(fb.e[4]), a1.y + __bfloat162float(fb.e[5]),
                a1.z + __bfloat162float(fb.e[6]), a1.w + __bfloat162float(fb.e[7])};
  float sum = 0.f, sq = 0.f;
#pragma unroll
  for (int j = 0; j < 8; ++j) { sum += v[j]; sq += v[j] * v[j]; }
#pragma unroll
  for (int m = 1; m < 64; m <<= 1) {
    sum += __shfl_xor(sum, m);
    sq += __shfl_xor(sq, m);
  }
  float mean = sum * (1.f / 512.f);
  float var = sq * (1.f / 512.f) - mean * mean;
  float rs = rsqrtf(var + 1e-5f);
  float4 g0 = *(const float4*)(g + c);
  float4 g1v = *(const float4*)(g + c + 4);
  float4 e0 = *(const float4*)(be + c);
  float4 e1 = *(const float4*)(be + c + 4);
  float gg[8] = {g0.x, g0.y, g0.z, g0.w, g1v.x, g1v.y, g1v.z, g1v.w};
  float ee[8] = {e0.x, e0.y, e0.z, e0.w, e1.x, e1.y, e1.z, e1.w};
  float y[8];
  __hip_bfloat16 hb[8];
#pragma unroll
  for (int j = 0; j < 8; ++j) {
    y[j] = (v[j] - mean) * rs * gg[j] + ee[j];
    hb[j] = __float2bfloat16(y[j]);
  }
  float4 o0 = {y[0], y[1], y[2], y[3]};
  float4 o1 = {y[4], y[5], y[6], y[7]};
  *(float4*)(xr + c) = o0;
  *(float4*)(xr + c + 4) = o1;
  *(uint4*)((char*)(xb + row * 512 + c)) = *(uint4*)hb;
}

// ---------------- setup / conversion kernels ------------------------------
__global__ void bfc(const float* __restrict__ xm, __hip_bfloat16* __restrict__ xb) {
  int i = blockIdx.x * 256 + threadIdx.x;
  float4 v = ((const float4*)xm)[i];
  __hip_bfloat16 hb[4] = {__float2bfloat16(v.x), __float2bfloat16(v.y),
                          __float2bfloat16(v.z), __float2bfloat16(v.w)};
  ((uint2*)xb)[i] = *(uint2*)hb;
}

__global__ void convq(const float* __restrict__ wq, __hip_bfloat16* __restrict__ o) {
  int i = blockIdx.x * 256 + threadIdx.x;  // over 6*1536*512/4 exactly
  float4 v = ((const float4*)wq)[i];
  int e = i * 4;
  float sc = (((e >> 9) % 1536) < 512) ? 0.125f : 1.f;
  __hip_bfloat16 hb[4] = {__float2bfloat16(v.x * sc), __float2bfloat16(v.y * sc),
                          __float2bfloat16(v.z * sc), __float2bfloat16(v.w * sc)};
  ((uint2*)o)[i] = *(uint2*)hb;
}

__global__ void convw(const float* __restrict__ s, __hip_bfloat16* __restrict__ o) {
  int i = blockIdx.x * 256 + threadIdx.x;  // exact grids only
  float4 v = ((const float4*)s)[i];
  __hip_bfloat16 hb[4] = {__float2bfloat16(v.x), __float2bfloat16(v.y),
                          __float2bfloat16(v.z), __float2bfloat16(v.w)};
  ((uint2*)o)[i] = *(uint2*)hb;
}

__global__ void scaleb(const float* __restrict__ b, float* __restrict__ o) {
  int i = blockIdx.x * 256 + threadIdx.x;  // over 9216 exactly
  o[i] = b[i] * (((i % 1536) < 512) ? 0.125f : 1.f);
}

// ---------------- launch ---------------------------------------------------
extern "C" void kernel_launch(void* const* d_in, const int* in_sizes, int n_in,
                              void* d_out, int out_size, void* d_ws, size_t ws_size,
                              hipStream_t stream) {
  const float* src  = (const float*)d_in[0];
  const float* Wqkv = (const float*)d_in[1];
  const float* bqkv = (const float*)d_in[2];
  const float* Wo   = (const float*)d_in[3];
  const float* bo   = (const float*)d_in[4];
  const float* W1   = (const float*)d_in[5];
  const float* bf1  = (const float*)d_in[6];
  const float* W2   = (const float*)d_in[7];
  const float* bf2  = (const float*)d_in[8];
  const float* g1   = (const float*)d_in[9];
  const float* be1  = (const float*)d_in[10];
  const float* g2   = (const float*)d_in[11];
  const float* be2  = (const float*)d_in[12];
  float* x = (float*)d_out;  // fp32 residual master == output

  char* ws = (char*)d_ws;
  size_t off = 0;
  auto alloc = [&](size_t bytes) {
    char* p = ws + off;
    off += (bytes + 255) & ~(size_t)255;
    return p;
  };

  const size_t wq_b = (size_t)L_ * D3 * D_ * 2;
  const size_t wo_b = (size_t)L_ * D_ * D_ * 2;
  const size_t w1_b = (size_t)L_ * DF * D_ * 2;
  const size_t w2_b = (size_t)L_ * D_ * DF * 2;
  auto al = [](size_t v) { return (v + 255) & ~(size_t)255; };
  const size_t persist = al(wq_b) + al(wo_b) + al(w1_b) + al(w2_b) + al(L_ * D3 * 4);

  int CT = NT;
  while (CT > 2048 && persist + (size_t)CT * 6144 + 65536 > ws_size) CT >>= 1;

  __hip_bfloat16* wqkvb = (__hip_bfloat16*)alloc(wq_b);
  __hip_bfloat16* wob   = (__hip_bfloat16*)alloc(wo_b);
  __hip_bfloat16* w1b   = (__hip_bfloat16*)alloc(w1_b);
  __hip_bfloat16* w2b   = (__hip_bfloat16*)alloc(w2_b);
  float*          bqs   = (float*)alloc((size_t)L_ * D3 * 4);
  __hip_bfloat16* xbf   = (__hip_bfloat16*)alloc((size_t)CT * 512 * 2);
  __hip_bfloat16* R     = (__hip_bfloat16*)alloc((size_t)CT * 2048 * 2);
  __hip_bfloat16* OB    = (__hip_bfloat16*)alloc((size_t)CT * 512 * 2);

  hipMemcpyAsync(x, src, (size_t)NT * 512 * 4, hipMemcpyDeviceToDevice, stream);
  convq<<<L_ * D3 * D_ / 4 / 256, 256, 0, stream>>>(Wqkv, wqkvb);
  convw<<<L_ * D_ * D_ / 4 / 256, 256, 0, stream>>>(Wo, wob);
  convw<<<L_ * DF * D_ / 4 / 256, 256, 0, stream>>>(W1, w1b);
  convw<<<L_ * D_ * DF / 4 / 256, 256, 0, stream>>>(W2, w2b);
  scaleb<<<L_ * D3 / 256, 256, 0, stream>>>(bqkv, bqs);

  const int nch = NT / CT;
  for (int c = 0; c < nch; ++c) {
    float* xm = x + (size_t)c * CT * 512;
    bfc<<<CT / 2, 256, 0, stream>>>(xm, xbf);
    for (int l = 0; l < L_; ++l) {
      // qkv -> R[0 .. CT*1536): 6 n-tiles, 3 tiles/block
      gemm256<512, 6, 3, false><<<CT / 128, 512, 0, stream>>>(
          xbf, wqkvb + (size_t)l * D3 * D_, bqs + l * D3, R);
      attn_win<<<CT / 16, 128, 0, stream>>>(R, OB);
      // o-proj -> R[0 .. CT*512)
      gemm256<512, 2, 1, false><<<CT / 128, 512, 0, stream>>>(
          OB, wob + (size_t)l * D_ * D_, bo + l * D_, R);
      ln_res<<<CT / 4, 256, 0, stream>>>(xm, R, g1 + l * D_, be1 + l * D_, xbf);
      // ffn1 -> R full: 8 n-tiles, 4 tiles/block
      gemm256<512, 8, 4, true><<<CT / 128, 512, 0, stream>>>(
          xbf, w1b + (size_t)l * DF * D_, bf1 + l * DF, R);
      // ffn2 -> OB
      gemm256<2048, 2, 1, false><<<CT / 128, 512, 0, stream>>>(
          R, w2b + (size_t)l * D_ * DF, bf2 + l * D_, OB);
      ln_res<<<CT / 4, 256, 0, stream>>>(xm, OB, g2 + l * D_, be2 + l * D_, xbf);
    }
  }
}

// Round 7
// 2012.330 us; speedup vs baseline: 1.0915x; 1.0915x over previous
//
#include <hip/hip_runtime.h>
#include <hip/hip_bf16.h>

typedef __bf16 bf16x8 __attribute__((ext_vector_type(8)));
typedef float f32x4 __attribute__((ext_vector_type(4)));

static constexpr int NT = 32768;  // S*B tokens
static constexpr int D_ = 512;
static constexpr int D3 = 1536;
static constexpr int DF = 2048;
static constexpr int L_ = 6;

#define AS1 __attribute__((address_space(1)))
#define AS3 __attribute__((address_space(3)))

__device__ __forceinline__ void gload_lds16(const void* g, void* l) {
  __builtin_amdgcn_global_load_lds((const AS1 void*)g, (AS3 void*)l, 16, 0, 0);
}

// ================= 256x256 8-phase GEMM: C = A[M,K] * W[N,K]^T + bias ======
// 8 waves (2M x 4N), per-wave 128x64 output. Schedule/ledger identical to the
// verified round-5 kernel (see comment there). This revision removes VALU
// from the steady-state critical path: all LDS fragment reads go through
// per-lane base pointers precomputed once (swizzle term is loop-invariant:
// r&7 == lrow&7 for every fragment row), with m/n as compile-time immediates;
// staging sources are per-lane bases + wave-uniform kt offsets (SALU).
template<int K, int NTN, bool RELU>
__global__ __launch_bounds__(512, 2) void gemm256(
    const __hip_bfloat16* __restrict__ A,
    const __hip_bfloat16* __restrict__ W,
    const float* __restrict__ bias,
    __hip_bfloat16* __restrict__ Cout) {
  __shared__ __align__(16) char lds[131072];
  const int t = threadIdx.x;
  const int l = t & 63, w = t >> 6;
  const int lrow = l & 15, lhi = l >> 4;
  const int wr = w >> 2, wc = w & 3;

  const int lin = blockIdx.x;
  const int wg = (lin & 7) * ((int)gridDim.x >> 3) + (lin >> 3);
  const int tm0 = (wg / NTN) * 256, tn0 = (wg % NTN) * 256;

  constexpr int NKT = K / 64;
  constexpr int NIT = NKT / 2;
  constexpr int N = NTN * 256;

  const int srow = t >> 3;  // 0..63
  const int sun = t & 7;

  // ---- loop-invariant address bases --------------------------------------
  // staging: src = base + kt*64 (+64*K for pass1, +128*K for second half)
  const int u8 = (sun ^ (srow & 7)) << 3;  // element offset, pass-invariant
  const __hip_bfloat16* sA = A + (size_t)(tm0 + srow) * K + u8;
  const __hip_bfloat16* sA2 = sA + (size_t)128 * K;
  const __hip_bfloat16* sW = W + (size_t)(tn0 + srow) * K + u8;
  const __hip_bfloat16* sW2 = sW + (size_t)128 * K;

  // fragment reads: addr = p[buf][ks] + (frag index)*2048 (immediate)
  const int lo = lrow * 128;
  const int x0 = (lhi ^ (lrow & 7)) << 4;
  const int x1 = ((4 + lhi) ^ (lrow & 7)) << 4;
  const char* pA[2][2];
  const char* pB[2][2];
  pA[0][0] = lds + (0 * 4 + wr) * 16384 + lo + x0;
  pA[0][1] = lds + (0 * 4 + wr) * 16384 + lo + x1;
  pA[1][0] = lds + (1 * 4 + wr) * 16384 + lo + x0;
  pA[1][1] = lds + (1 * 4 + wr) * 16384 + lo + x1;
  const int bo = (wc & 1) * 8192 + lo;
  pB[0][0] = lds + (0 * 4 + 2 + (wc >> 1)) * 16384 + bo + x0;
  pB[0][1] = lds + (0 * 4 + 2 + (wc >> 1)) * 16384 + bo + x1;
  pB[1][0] = lds + (1 * 4 + 2 + (wc >> 1)) * 16384 + bo + x0;
  pB[1][1] = lds + (1 * 4 + 2 + (wc >> 1)) * 16384 + bo + x1;

  // stage one 128x64 half-tile (2 x gload_lds16); s = sA/sA2/sW/sW2
  auto stage = [&](int buf, int reg, const __hip_bfloat16* s, int kt) {
    char* dst = lds + (buf * 4 + reg) * 16384 + w * 1024;
    const __hip_bfloat16* src = s + kt * 64;
    gload_lds16(src, dst);
    gload_lds16(src + (size_t)64 * K, dst + 8192);
  };

  f32x4 acc[8][4] = {};
  bf16x8 bfrag[4][2], afrag[2][2];

  // ---- prologue: t0 complete + t1.B halves; force t0 landed
  stage(0, 2, sW, 0);
  stage(0, 3, sW2, 0);
  stage(0, 0, sA, 0);
  stage(0, 1, sA2, 0);
  stage(1, 2, sW, 1);
  stage(1, 3, sW2, 1);
  asm volatile("s_waitcnt vmcnt(4)" ::: "memory");
  __builtin_amdgcn_s_barrier();

#define GPHASE(BUF, MB, RB, STG, VMS)                                       \
  {                                                                          \
    if (RB) {                                                                \
      _Pragma("unroll") for (int n = 0; n < 4; ++n)                          \
          _Pragma("unroll") for (int ks = 0; ks < 2; ++ks)                   \
              bfrag[n][ks] = *(const bf16x8*)(pB[BUF][ks] + n * 2048);       \
    }                                                                        \
    _Pragma("unroll") for (int ks = 0; ks < 2; ++ks) {                       \
      afrag[0][ks] = *(const bf16x8*)(pA[BUF][ks] + MB * 2048);              \
      afrag[1][ks] = *(const bf16x8*)(pA[BUF][ks] + (MB + 1) * 2048);        \
    }                                                                        \
    STG;                                                                     \
    VMS;                                                                     \
    __builtin_amdgcn_sched_barrier(0);                                       \
    __builtin_amdgcn_s_barrier();                                            \
    asm volatile("s_waitcnt lgkmcnt(0)" ::: "memory");                       \
    __builtin_amdgcn_sched_barrier(0);                                       \
    __builtin_amdgcn_s_setprio(1);                                           \
    _Pragma("unroll") for (int n = 0; n < 4; ++n)                            \
        _Pragma("unroll") for (int ks = 0; ks < 2; ++ks) {                   \
      acc[MB][n] = __builtin_amdgcn_mfma_f32_16x16x32_bf16(                  \
          afrag[0][ks], bfrag[n][ks], acc[MB][n], 0, 0, 0);                  \
      acc[MB + 1][n] = __builtin_amdgcn_mfma_f32_16x16x32_bf16(              \
          afrag[1][ks], bfrag[n][ks], acc[MB + 1][n], 0, 0, 0);              \
    }                                                                        \
    __builtin_amdgcn_s_setprio(0);                                           \
    __builtin_amdgcn_sched_barrier(0);                                       \
    __builtin_amdgcn_s_barrier();                                            \
  }

#define VM_CNT                                              \
  if (more) {                                               \
    asm volatile("s_waitcnt vmcnt(4)" ::: "memory");        \
  } else {                                                  \
    asm volatile("s_waitcnt vmcnt(0)" ::: "memory");        \
  }

  for (int it = 0; it < NIT; ++it) {
    const int t1 = 2 * it + 1;
    const bool more = (it + 1 < NIT);
    // K-tile t0 from buf0
    GPHASE(0, 0, 1, { stage(1, 0, sA, t1); stage(1, 1, sA2, t1); }, );
    GPHASE(0, 2, 0, { if (more) stage(0, 2, sW, t1 + 1); }, );
    GPHASE(0, 4, 0, { if (more) stage(0, 3, sW2, t1 + 1); }, );
    GPHASE(0, 6, 0, , VM_CNT);
    // K-tile t1 from buf1
    GPHASE(1, 0, 1, { if (more) stage(0, 0, sA, t1 + 1); }, );
    GPHASE(1, 2, 0, { if (more) stage(0, 1, sA2, t1 + 1); }, );
    GPHASE(1, 4, 0, { if (more) stage(1, 2, sW, t1 + 2); }, );
    GPHASE(1, 6, 0, { if (more) stage(1, 3, sW2, t1 + 2); }, VM_CNT);
  }
#undef GPHASE
#undef VM_CNT

  // ---- epilogue: wave-private LDS transpose (unit-XOR swizzled), uint4 stores
  char* ep = lds + w * 16384;  // 128x64 bf16, row stride 128B
#pragma unroll
  for (int n = 0; n < 4; ++n) {
    float bv = bias[tn0 + wc * 64 + n * 16 + lrow];
#pragma unroll
    for (int m = 0; m < 8; ++m)
#pragma unroll
      for (int j = 0; j < 4; ++j) {
        float v = acc[m][n][j] + bv;
        if (RELU) v = fmaxf(v, 0.f);
        int row = m * 16 + lhi * 4 + j;
        int col = n * 16 + lrow;
        *(__hip_bfloat16*)(ep + row * 128 + (((col >> 3) ^ (row & 7)) << 4) +
                           (col & 7) * 2) = __float2bfloat16(v);
      }
  }
  __builtin_amdgcn_sched_barrier(0);
  const int er = l >> 3, ec = l & 7;
#pragma unroll
  for (int p = 0; p < 16; ++p) {
    int r = p * 8 + er;
    uint4 vv = *(const uint4*)(ep + r * 128 + ((ec ^ (r & 7)) << 4));
    *(uint4*)&Cout[(size_t)(tm0 + wr * 128 + r) * N + tn0 + wc * 64 + ec * 8] = vv;
  }
}

// ---------------- Windowed attention: one wave per (window, b, h) --------
// qkv: [CT, 1536] bf16 (q pre-scaled by 1/8 via weight folding). o: [CT,512].
__global__ __launch_bounds__(128) void attn_win(
    const __hip_bfloat16* __restrict__ qkv, __hip_bfloat16* __restrict__ o) {
  __shared__ __align__(16) char lds[2 * 18432];
  const int t = threadIdx.x, l = t & 63, w = t >> 6;
  char* vt = lds + w * 18432;          // Vt[d][k], stride 72 bf16
  char* pl = vt + 9216;                // P[q][k],  stride 72 bf16
  const int wid = blockIdx.x * 2 + w;
  const int h = wid & 7, b = (wid >> 3) & 3, nw = wid >> 5;
  const int lrow = l & 15, lhi = l >> 4;
  const __hip_bfloat16* qp = qkv + (size_t)(nw * 256 + b) * 1536 + h * 64;
  const __hip_bfloat16* kp = qp + 512;
  const __hip_bfloat16* vp = qp + 1024;

  // stage V transposed into LDS
  {
    const int d0 = (l & 7) * 8;
    const int r0 = l >> 3;
#pragma unroll
    for (int i = 0; i < 8; ++i) {
      int r = r0 + i * 8;
      union { uint4 u; __hip_bfloat16 e[8]; } vv;
      vv.u = *(const uint4*)(vp + (size_t)r * 6144 + d0);
#pragma unroll
      for (int j = 0; j < 8; ++j)
        *(__hip_bfloat16*)(vt + ((d0 + j) * 72 + r) * 2) = vv.e[j];
    }
  }

  // Q/K fragments straight from global
  bf16x8 qf[4][2], kf[4][2];
#pragma unroll
  for (int mi = 0; mi < 4; ++mi)
#pragma unroll
    for (int ks = 0; ks < 2; ++ks) {
      int r = mi * 16 + lrow;
      int d = ks * 32 + lhi * 8;
      qf[mi][ks] = __builtin_bit_cast(bf16x8, *(const uint4*)(qp + (size_t)r * 6144 + d));
      kf[mi][ks] = __builtin_bit_cast(bf16x8, *(const uint4*)(kp + (size_t)r * 6144 + d));
    }

  // S = Q K^T  (64x64)
  f32x4 s[4][4] = {};
#pragma unroll
  for (int mi = 0; mi < 4; ++mi)
#pragma unroll
    for (int ni = 0; ni < 4; ++ni) {
      s[mi][ni] = __builtin_amdgcn_mfma_f32_16x16x32_bf16(qf[mi][0], kf[ni][0], s[mi][ni], 0, 0, 0);
      s[mi][ni] = __builtin_amdgcn_mfma_f32_16x16x32_bf16(qf[mi][1], kf[ni][1], s[mi][ni], 0, 0, 0);
    }

  // softmax over k (cols)
#pragma unroll
  for (int mi = 0; mi < 4; ++mi)
#pragma unroll
    for (int j = 0; j < 4; ++j) {
      float mx = s[mi][0][j];
#pragma unroll
      for (int ni = 1; ni < 4; ++ni) mx = fmaxf(mx, s[mi][ni][j]);
      mx = fmaxf(mx, __shfl_xor(mx, 1));
      mx = fmaxf(mx, __shfl_xor(mx, 2));
      mx = fmaxf(mx, __shfl_xor(mx, 4));
      mx = fmaxf(mx, __shfl_xor(mx, 8));
      float p[4], sum = 0.f;
#pragma unroll
      for (int ni = 0; ni < 4; ++ni) { p[ni] = __expf(s[mi][ni][j] - mx); sum += p[ni]; }
      sum += __shfl_xor(sum, 1);
      sum += __shfl_xor(sum, 2);
      sum += __shfl_xor(sum, 4);
      sum += __shfl_xor(sum, 8);
      float inv = 1.f / sum;
      int row = mi * 16 + lhi * 4 + j;
#pragma unroll
      for (int ni = 0; ni < 4; ++ni)
        *(__hip_bfloat16*)(pl + (row * 72 + ni * 16 + lrow) * 2) =
            __float2bfloat16(p[ni] * inv);
    }

  // O = P V
  bf16x8 pf[4][2], vf[4][2];
#pragma unroll
  for (int mi = 0; mi < 4; ++mi)
#pragma unroll
    for (int ks = 0; ks < 2; ++ks)
      pf[mi][ks] = *(const bf16x8*)(pl + ((mi * 16 + lrow) * 72 + ks * 32 + lhi * 8) * 2);
#pragma unroll
  for (int ni = 0; ni < 4; ++ni)
#pragma unroll
    for (int ks = 0; ks < 2; ++ks)
      vf[ni][ks] = *(const bf16x8*)(vt + ((ni * 16 + lrow) * 72 + ks * 32 + lhi * 8) * 2);

  f32x4 acc[4][4] = {};
#pragma unroll
  for (int mi = 0; mi < 4; ++mi)
#pragma unroll
    for (int ni = 0; ni < 4; ++ni) {
      acc[mi][ni] = __builtin_amdgcn_mfma_f32_16x16x32_bf16(pf[mi][0], vf[ni][0], acc[mi][ni], 0, 0, 0);
      acc[mi][ni] = __builtin_amdgcn_mfma_f32_16x16x32_bf16(pf[mi][1], vf[ni][1], acc[mi][ni], 0, 0, 0);
    }

  __hip_bfloat16* op = o + (size_t)(nw * 256 + b) * 512 + h * 64;
#pragma unroll
  for (int mi = 0; mi < 4; ++mi)
#pragma unroll
    for (int ni = 0; ni < 4; ++ni) {
      int col = ni * 16 + lrow;
#pragma unroll
      for (int j = 0; j < 4; ++j) {
        int row = mi * 16 + lhi * 4 + j;
        op[(size_t)row * 2048 + col] = __float2bfloat16(acc[mi][ni][j]);
      }
    }
}

// ---------------- residual + LayerNorm (wave per row of 512) -------------
__global__ __launch_bounds__(256) void ln_res(
    float* __restrict__ x, const __hip_bfloat16* __restrict__ f,
    const float* __restrict__ g, const float* __restrict__ be,
    __hip_bfloat16* __restrict__ xb) {
  const int w = threadIdx.x >> 6, l = threadIdx.x & 63;
  const size_t row = (size_t)blockIdx.x * 4 + w;
  float* xr = x + row * 512;
  const int c = l * 8;
  float4 a0 = *(const float4*)(xr + c);
  float4 a1 = *(const float4*)(xr + c + 4);
  union { uint4 u; __hip_bfloat16 e[8]; } fb;
  fb.u = *(const uint4*)(f + row * 512 + c);
  float v[8] = {a0.x + __bfloat162float(fb.e[0]), a0.y + __bfloat162float(fb.e[1]),
                a0.z + __bfloat162float(fb.e[2]), a0.w + __bfloat162float(fb.e[3]),
                a1.x + __bfloat162float(fb.e[4]), a1.y + __bfloat162float(fb.e[5]),
                a1.z + __bfloat162float(fb.e[6]), a1.w + __bfloat162float(fb.e[7])};
  float sum = 0.f, sq = 0.f;
#pragma unroll
  for (int j = 0; j < 8; ++j) { sum += v[j]; sq += v[j] * v[j]; }
#pragma unroll
  for (int m = 1; m < 64; m <<= 1) {
    sum += __shfl_xor(sum, m);
    sq += __shfl_xor(sq, m);
  }
  float mean = sum * (1.f / 512.f);
  float var = sq * (1.f / 512.f) - mean * mean;
  float rs = rsqrtf(var + 1e-5f);
  float4 g0 = *(const float4*)(g + c);
  float4 g1v = *(const float4*)(g + c + 4);
  float4 e0 = *(const float4*)(be + c);
  float4 e1 = *(const float4*)(be + c + 4);
  float gg[8] = {g0.x, g0.y, g0.z, g0.w, g1v.x, g1v.y, g1v.z, g1v.w};
  float ee[8] = {e0.x, e0.y, e0.z, e0.w, e1.x, e1.y, e1.z, e1.w};
  float y[8];
  __hip_bfloat16 hb[8];
#pragma unroll
  for (int j = 0; j < 8; ++j) {
    y[j] = (v[j] - mean) * rs * gg[j] + ee[j];
    hb[j] = __float2bfloat16(y[j]);
  }
  float4 o0 = {y[0], y[1], y[2], y[3]};
  float4 o1 = {y[4], y[5], y[6], y[7]};
  *(float4*)(xr + c) = o0;
  *(float4*)(xr + c + 4) = o1;
  *(uint4*)((char*)(xb + row * 512 + c)) = *(uint4*)hb;
}

// ---------------- setup / conversion kernels ------------------------------
__global__ void bfc(const float* __restrict__ xm, __hip_bfloat16* __restrict__ xb) {
  int i = blockIdx.x * 256 + threadIdx.x;
  float4 v = ((const float4*)xm)[i];
  __hip_bfloat16 hb[4] = {__float2bfloat16(v.x), __float2bfloat16(v.y),
                          __float2bfloat16(v.z), __float2bfloat16(v.w)};
  ((uint2*)xb)[i] = *(uint2*)hb;
}

__global__ void convq(const float* __restrict__ wq, __hip_bfloat16* __restrict__ o) {
  int i = blockIdx.x * 256 + threadIdx.x;  // over 6*1536*512/4 exactly
  float4 v = ((const float4*)wq)[i];
  int e = i * 4;
  float sc = (((e >> 9) % 1536) < 512) ? 0.125f : 1.f;
  __hip_bfloat16 hb[4] = {__float2bfloat16(v.x * sc), __float2bfloat16(v.y * sc),
                          __float2bfloat16(v.z * sc), __float2bfloat16(v.w * sc)};
  ((uint2*)o)[i] = *(uint2*)hb;
}

__global__ void convw(const float* __restrict__ s, __hip_bfloat16* __restrict__ o) {
  int i = blockIdx.x * 256 + threadIdx.x;  // exact grids only
  float4 v = ((const float4*)s)[i];
  __hip_bfloat16 hb[4] = {__float2bfloat16(v.x), __float2bfloat16(v.y),
                          __float2bfloat16(v.z), __float2bfloat16(v.w)};
  ((uint2*)o)[i] = *(uint2*)hb;
}

__global__ void scaleb(const float* __restrict__ b, float* __restrict__ o) {
  int i = blockIdx.x * 256 + threadIdx.x;  // over 9216 exactly
  o[i] = b[i] * (((i % 1536) < 512) ? 0.125f : 1.f);
}

// ---------------- launch ---------------------------------------------------
extern "C" void kernel_launch(void* const* d_in, const int* in_sizes, int n_in,
                              void* d_out, int out_size, void* d_ws, size_t ws_size,
                              hipStream_t stream) {
  const float* src  = (const float*)d_in[0];
  const float* Wqkv = (const float*)d_in[1];
  const float* bqkv = (const float*)d_in[2];
  const float* Wo   = (const float*)d_in[3];
  const float* bo   = (const float*)d_in[4];
  const float* W1   = (const float*)d_in[5];
  const float* bf1  = (const float*)d_in[6];
  const float* W2   = (const float*)d_in[7];
  const float* bf2  = (const float*)d_in[8];
  const float* g1   = (const float*)d_in[9];
  const float* be1  = (const float*)d_in[10];
  const float* g2   = (const float*)d_in[11];
  const float* be2  = (const float*)d_in[12];
  float* x = (float*)d_out;  // fp32 residual master == output

  char* ws = (char*)d_ws;
  size_t off = 0;
  auto alloc = [&](size_t bytes) {
    char* p = ws + off;
    off += (bytes + 255) & ~(size_t)255;
    return p;
  };

  const size_t wq_b = (size_t)L_ * D3 * D_ * 2;
  const size_t wo_b = (size_t)L_ * D_ * D_ * 2;
  const size_t w1_b = (size_t)L_ * DF * D_ * 2;
  const size_t w2_b = (size_t)L_ * D_ * DF * 2;
  auto al = [](size_t v) { return (v + 255) & ~(size_t)255; };
  const size_t persist = al(wq_b) + al(wo_b) + al(w1_b) + al(w2_b) + al(L_ * D3 * 4);

  int CT = NT;
  while (CT > 2048 && persist + (size_t)CT * 6144 + 65536 > ws_size) CT >>= 1;

  __hip_bfloat16* wqkvb = (__hip_bfloat16*)alloc(wq_b);
  __hip_bfloat16* wob   = (__hip_bfloat16*)alloc(wo_b);
  __hip_bfloat16* w1b   = (__hip_bfloat16*)alloc(w1_b);
  __hip_bfloat16* w2b   = (__hip_bfloat16*)alloc(w2_b);
  float*          bqs   = (float*)alloc((size_t)L_ * D3 * 4);
  __hip_bfloat16* xbf   = (__hip_bfloat16*)alloc((size_t)CT * 512 * 2);
  __hip_bfloat16* R     = (__hip_bfloat16*)alloc((size_t)CT * 2048 * 2);
  __hip_bfloat16* OB    = (__hip_bfloat16*)alloc((size_t)CT * 512 * 2);

  hipMemcpyAsync(x, src, (size_t)NT * 512 * 4, hipMemcpyDeviceToDevice, stream);
  convq<<<L_ * D3 * D_ / 4 / 256, 256, 0, stream>>>(Wqkv, wqkvb);
  convw<<<L_ * D_ * D_ / 4 / 256, 256, 0, stream>>>(Wo, wob);
  convw<<<L_ * DF * D_ / 4 / 256, 256, 0, stream>>>(W1, w1b);
  convw<<<L_ * D_ * DF / 4 / 256, 256, 0, stream>>>(W2, w2b);
  scaleb<<<L_ * D3 / 256, 256, 0, stream>>>(bqkv, bqs);

  const int nch = NT / CT;
  for (int c = 0; c < nch; ++c) {
    float* xm = x + (size_t)c * CT * 512;
    bfc<<<CT / 2, 256, 0, stream>>>(xm, xbf);
    for (int l = 0; l < L_; ++l) {
      // qkv -> R[0 .. CT*1536)
      gemm256<512, 6, false><<<(CT / 256) * 6, 512, 0, stream>>>(
          xbf, wqkvb + (size_t)l * D3 * D_, bqs + l * D3, R);
      attn_win<<<CT / 16, 128, 0, stream>>>(R, OB);
      // o-proj -> R[0 .. CT*512)
      gemm256<512, 2, false><<<(CT / 256) * 2, 512, 0, stream>>>(
          OB, wob + (size_t)l * D_ * D_, bo + l * D_, R);
      ln_res<<<CT / 4, 256, 0, stream>>>(xm, R, g1 + l * D_, be1 + l * D_, xbf);
      // ffn1 -> R full
      gemm256<512, 8, true><<<(CT / 256) * 8, 512, 0, stream>>>(
          xbf, w1b + (size_t)l * DF * D_, bf1 + l * DF, R);
      // ffn2 -> OB
      gemm256<2048, 2, false><<<(CT / 256) * 2, 512, 0, stream>>>(
          R, w2b + (size_t)l * D_ * DF, bf2 + l * D_, OB);
      ln_res<<<CT / 4, 256, 0, stream>>>(xm, OB, g2 + l * D_, be2 + l * D_, xbf);
    }
  }
}

// Round 8
// 1819.029 us; speedup vs baseline: 1.2075x; 1.1063x over previous
//
#include <hip/hip_runtime.h>
#include <hip/hip_bf16.h>

typedef __bf16 bf16x8 __attribute__((ext_vector_type(8)));
typedef float f32x4 __attribute__((ext_vector_type(4)));

static constexpr int NT = 32768;  // S*B tokens
static constexpr int D_ = 512;
static constexpr int D3 = 1536;
static constexpr int DF = 2048;
static constexpr int L_ = 6;

#define AS1 __attribute__((address_space(1)))
#define AS3 __attribute__((address_space(3)))

__device__ __forceinline__ void gload_lds16(const void* g, void* l) {
  __builtin_amdgcn_global_load_lds((const AS1 void*)g, (AS3 void*)l, 16, 0, 0);
}

// ========== 256x256 merged-4-phase GEMM: C = A[M,K] * W[N,K]^T + bias ======
// 8 waves (2M x 4N), per-wave 128x64 output. Iteration = 2 K-tiles = 4 fat
// phases of 32 MFMA; ONE barrier per phase (write-after-read safety: readers
// of a region complete at their own lgkmcnt(0) before their MFMA, hence
// before the phase-closing barrier; every stage targets a region not read in
// its own phase, so it is issued after that barrier). Data-ready is
// collective: vmcnt precedes the closing barrier.
// Ledger (regions: buf*4 + {0,1}=A halves, {2,3}=B halves):
//   MPH1 reads buf0.B + buf0.A(MB0-3); stages buf1.A <- t1
//   MPH2 reads buf0.A(MB4-7);          stages buf0.B <- t0+2; vmcnt(4)
//   MPH3 reads buf1.B + buf1.A(MB0-3); stages buf0.A <- t0+2
//   MPH4 reads buf1.A(MB4-7);          stages buf1.B <- t1+2; vmcnt(4)
// vmcnt(4) leaves only the current phase's 4 loads outstanding (in-order
// retire), confirming everything the next reader phase needs. vmcnt(0) on
// the final iteration; epilogue reuses LDS after the last barrier.
template<int K, int NTN, bool RELU>
__global__ __launch_bounds__(512, 2) void gemm256(
    const __hip_bfloat16* __restrict__ A,
    const __hip_bfloat16* __restrict__ W,
    const float* __restrict__ bias,
    __hip_bfloat16* __restrict__ Cout) {
  __shared__ __align__(16) char lds[131072];
  const int t = threadIdx.x;
  const int l = t & 63, w = t >> 6;
  const int lrow = l & 15, lhi = l >> 4;
  const int wr = w >> 2, wc = w & 3;

  const int lin = blockIdx.x;
  const int wg = (lin & 7) * ((int)gridDim.x >> 3) + (lin >> 3);
  const int tm0 = (wg / NTN) * 256, tn0 = (wg % NTN) * 256;

  constexpr int NKT = K / 64;
  constexpr int NIT = NKT / 2;
  constexpr int N = NTN * 256;

  const int srow = t >> 3;
  const int sun = t & 7;

  // loop-invariant staging bases: src = base + kt*64 (+64*K second pass)
  const int u8 = (sun ^ (srow & 7)) << 3;
  const __hip_bfloat16* sA = A + (size_t)(tm0 + srow) * K + u8;
  const __hip_bfloat16* sA2 = sA + (size_t)128 * K;
  const __hip_bfloat16* sW = W + (size_t)(tn0 + srow) * K + u8;
  const __hip_bfloat16* sW2 = sW + (size_t)128 * K;

  // loop-invariant fragment-read bases (swizzle term r&7 == lrow&7)
  const int lo = lrow * 128;
  const int x0 = (lhi ^ (lrow & 7)) << 4;
  const int x1 = ((4 + lhi) ^ (lrow & 7)) << 4;
  const char* pA[2][2];
  const char* pB[2][2];
  pA[0][0] = lds + (0 * 4 + wr) * 16384 + lo + x0;
  pA[0][1] = lds + (0 * 4 + wr) * 16384 + lo + x1;
  pA[1][0] = lds + (1 * 4 + wr) * 16384 + lo + x0;
  pA[1][1] = lds + (1 * 4 + wr) * 16384 + lo + x1;
  const int bo = (wc & 1) * 8192 + lo;
  pB[0][0] = lds + (0 * 4 + 2 + (wc >> 1)) * 16384 + bo + x0;
  pB[0][1] = lds + (0 * 4 + 2 + (wc >> 1)) * 16384 + bo + x1;
  pB[1][0] = lds + (1 * 4 + 2 + (wc >> 1)) * 16384 + bo + x0;
  pB[1][1] = lds + (1 * 4 + 2 + (wc >> 1)) * 16384 + bo + x1;

  auto stage = [&](int buf, int reg, const __hip_bfloat16* s, int kt) {
    char* dst = lds + (buf * 4 + reg) * 16384 + w * 1024;
    const __hip_bfloat16* src = s + kt * 64;
    gload_lds16(src, dst);
    gload_lds16(src + (size_t)64 * K, dst + 8192);
  };

  f32x4 acc[8][4] = {};
  bf16x8 bfrag[4][2], afrag[4][2];

  // ---- prologue: t0 complete + t1.B; force t0 landed
  stage(0, 2, sW, 0);
  stage(0, 3, sW2, 0);
  stage(0, 0, sA, 0);
  stage(0, 1, sA2, 0);
  stage(1, 2, sW, 1);
  stage(1, 3, sW2, 1);
  asm volatile("s_waitcnt vmcnt(4)" ::: "memory");
  __builtin_amdgcn_sched_barrier(0);
  __builtin_amdgcn_s_barrier();
  __builtin_amdgcn_sched_barrier(0);

#define MPHASE(BUF, RB, MB0, MB1, MB2, MB3, STG, VMS)                       \
  {                                                                          \
    STG;                                                                     \
    if (RB) {                                                                \
      _Pragma("unroll") for (int n = 0; n < 4; ++n)                          \
          _Pragma("unroll") for (int ks = 0; ks < 2; ++ks)                   \
              bfrag[n][ks] = *(const bf16x8*)(pB[BUF][ks] + n * 2048);       \
    }                                                                        \
    _Pragma("unroll") for (int ks = 0; ks < 2; ++ks) {                       \
      afrag[0][ks] = *(const bf16x8*)(pA[BUF][ks] + MB0 * 2048);             \
      afrag[1][ks] = *(const bf16x8*)(pA[BUF][ks] + MB1 * 2048);             \
      afrag[2][ks] = *(const bf16x8*)(pA[BUF][ks] + MB2 * 2048);             \
      afrag[3][ks] = *(const bf16x8*)(pA[BUF][ks] + MB3 * 2048);             \
    }                                                                        \
    asm volatile("s_waitcnt lgkmcnt(0)" ::: "memory");                       \
    __builtin_amdgcn_sched_barrier(0);                                       \
    __builtin_amdgcn_s_setprio(1);                                           \
    _Pragma("unroll") for (int n = 0; n < 4; ++n)                            \
        _Pragma("unroll") for (int ks = 0; ks < 2; ++ks) {                   \
      acc[MB0][n] = __builtin_amdgcn_mfma_f32_16x16x32_bf16(                 \
          afrag[0][ks], bfrag[n][ks], acc[MB0][n], 0, 0, 0);                 \
      acc[MB1][n] = __builtin_amdgcn_mfma_f32_16x16x32_bf16(                 \
          afrag[1][ks], bfrag[n][ks], acc[MB1][n], 0, 0, 0);                 \
      acc[MB2][n] = __builtin_amdgcn_mfma_f32_16x16x32_bf16(                 \
          afrag[2][ks], bfrag[n][ks], acc[MB2][n], 0, 0, 0);                 \
      acc[MB3][n] = __builtin_amdgcn_mfma_f32_16x16x32_bf16(                 \
          afrag[3][ks], bfrag[n][ks], acc[MB3][n], 0, 0, 0);                 \
    }                                                                        \
    __builtin_amdgcn_s_setprio(0);                                           \
    VMS;                                                                     \
    __builtin_amdgcn_sched_barrier(0);                                       \
    __builtin_amdgcn_s_barrier();                                            \
    __builtin_amdgcn_sched_barrier(0);                                       \
  }

#define VM_CNT                                              \
  if (more) {                                               \
    asm volatile("s_waitcnt vmcnt(4)" ::: "memory");        \
  } else {                                                  \
    asm volatile("s_waitcnt vmcnt(0)" ::: "memory");        \
  }

  for (int it = 0; it < NIT; ++it) {
    const int t1 = 2 * it + 1;
    const bool more = (it + 1 < NIT);
    MPHASE(0, 1, 0, 1, 2, 3,
           { stage(1, 0, sA, t1); stage(1, 1, sA2, t1); }, );
    MPHASE(0, 0, 4, 5, 6, 7,
           { if (more) { stage(0, 2, sW, t1 + 1); stage(0, 3, sW2, t1 + 1); } },
           VM_CNT);
    MPHASE(1, 1, 0, 1, 2, 3,
           { if (more) { stage(0, 0, sA, t1 + 1); stage(0, 1, sA2, t1 + 1); } }, );
    MPHASE(1, 0, 4, 5, 6, 7,
           { if (more) { stage(1, 2, sW, t1 + 2); stage(1, 3, sW2, t1 + 2); } },
           VM_CNT);
  }
#undef MPHASE
#undef VM_CNT

  // ---- epilogue: wave-private LDS transpose (unit-XOR swizzled), uint4 stores
  char* ep = lds + w * 16384;  // 128x64 bf16, row stride 128B
#pragma unroll
  for (int n = 0; n < 4; ++n) {
    float bv = bias[tn0 + wc * 64 + n * 16 + lrow];
#pragma unroll
    for (int m = 0; m < 8; ++m)
#pragma unroll
      for (int j = 0; j < 4; ++j) {
        float v = acc[m][n][j] + bv;
        if (RELU) v = fmaxf(v, 0.f);
        int row = m * 16 + lhi * 4 + j;
        int col = n * 16 + lrow;
        *(__hip_bfloat16*)(ep + row * 128 + (((col >> 3) ^ (row & 7)) << 4) +
                           (col & 7) * 2) = __float2bfloat16(v);
      }
  }
  __builtin_amdgcn_sched_barrier(0);
  const int er = l >> 3, ec = l & 7;
#pragma unroll
  for (int p = 0; p < 16; ++p) {
    int r = p * 8 + er;
    uint4 vv = *(const uint4*)(ep + r * 128 + ((ec ^ (r & 7)) << 4));
    *(uint4*)&Cout[(size_t)(tm0 + wr * 128 + r) * N + tn0 + wc * 64 + ec * 8] = vv;
  }
}

// ---------------- Windowed attention: one wave per (window, b, h) --------
__global__ __launch_bounds__(128) void attn_win(
    const __hip_bfloat16* __restrict__ qkv, __hip_bfloat16* __restrict__ o) {
  __shared__ __align__(16) char lds[2 * 18432];
  const int t = threadIdx.x, l = t & 63, w = t >> 6;
  char* vt = lds + w * 18432;          // Vt[d][k], stride 72 bf16
  char* pl = vt + 9216;                // P[q][k],  stride 72 bf16
  const int wid = blockIdx.x * 2 + w;
  const int h = wid & 7, b = (wid >> 3) & 3, nw = wid >> 5;
  const int lrow = l & 15, lhi = l >> 4;
  const __hip_bfloat16* qp = qkv + (size_t)(nw * 256 + b) * 1536 + h * 64;
  const __hip_bfloat16* kp = qp + 512;
  const __hip_bfloat16* vp = qp + 1024;

  {
    const int d0 = (l & 7) * 8;
    const int r0 = l >> 3;
#pragma unroll
    for (int i = 0; i < 8; ++i) {
      int r = r0 + i * 8;
      union { uint4 u; __hip_bfloat16 e[8]; } vv;
      vv.u = *(const uint4*)(vp + (size_t)r * 6144 + d0);
#pragma unroll
      for (int j = 0; j < 8; ++j)
        *(__hip_bfloat16*)(vt + ((d0 + j) * 72 + r) * 2) = vv.e[j];
    }
  }

  bf16x8 qf[4][2], kf[4][2];
#pragma unroll
  for (int mi = 0; mi < 4; ++mi)
#pragma unroll
    for (int ks = 0; ks < 2; ++ks) {
      int r = mi * 16 + lrow;
      int d = ks * 32 + lhi * 8;
      qf[mi][ks] = __builtin_bit_cast(bf16x8, *(const uint4*)(qp + (size_t)r * 6144 + d));
      kf[mi][ks] = __builtin_bit_cast(bf16x8, *(const uint4*)(kp + (size_t)r * 6144 + d));
    }

  f32x4 s[4][4] = {};
#pragma unroll
  for (int mi = 0; mi < 4; ++mi)
#pragma unroll
    for (int ni = 0; ni < 4; ++ni) {
      s[mi][ni] = __builtin_amdgcn_mfma_f32_16x16x32_bf16(qf[mi][0], kf[ni][0], s[mi][ni], 0, 0, 0);
      s[mi][ni] = __builtin_amdgcn_mfma_f32_16x16x32_bf16(qf[mi][1], kf[ni][1], s[mi][ni], 0, 0, 0);
    }

#pragma unroll
  for (int mi = 0; mi < 4; ++mi)
#pragma unroll
    for (int j = 0; j < 4; ++j) {
      float mx = s[mi][0][j];
#pragma unroll
      for (int ni = 1; ni < 4; ++ni) mx = fmaxf(mx, s[mi][ni][j]);
      mx = fmaxf(mx, __shfl_xor(mx, 1));
      mx = fmaxf(mx, __shfl_xor(mx, 2));
      mx = fmaxf(mx, __shfl_xor(mx, 4));
      mx = fmaxf(mx, __shfl_xor(mx, 8));
      float p[4], sum = 0.f;
#pragma unroll
      for (int ni = 0; ni < 4; ++ni) { p[ni] = __expf(s[mi][ni][j] - mx); sum += p[ni]; }
      sum += __shfl_xor(sum, 1);
      sum += __shfl_xor(sum, 2);
      sum += __shfl_xor(sum, 4);
      sum += __shfl_xor(sum, 8);
      float inv = 1.f / sum;
      int row = mi * 16 + lhi * 4 + j;
#pragma unroll
      for (int ni = 0; ni < 4; ++ni)
        *(__hip_bfloat16*)(pl + (row * 72 + ni * 16 + lrow) * 2) =
            __float2bfloat16(p[ni] * inv);
    }

  bf16x8 pf[4][2], vf[4][2];
#pragma unroll
  for (int mi = 0; mi < 4; ++mi)
#pragma unroll
    for (int ks = 0; ks < 2; ++ks)
      pf[mi][ks] = *(const bf16x8*)(pl + ((mi * 16 + lrow) * 72 + ks * 32 + lhi * 8) * 2);
#pragma unroll
  for (int ni = 0; ni < 4; ++ni)
#pragma unroll
    for (int ks = 0; ks < 2; ++ks)
      vf[ni][ks] = *(const bf16x8*)(vt + ((ni * 16 + lrow) * 72 + ks * 32 + lhi * 8) * 2);

  f32x4 acc[4][4] = {};
#pragma unroll
  for (int mi = 0; mi < 4; ++mi)
#pragma unroll
    for (int ni = 0; ni < 4; ++ni) {
      acc[mi][ni] = __builtin_amdgcn_mfma_f32_16x16x32_bf16(pf[mi][0], vf[ni][0], acc[mi][ni], 0, 0, 0);
      acc[mi][ni] = __builtin_amdgcn_mfma_f32_16x16x32_bf16(pf[mi][1], vf[ni][1], acc[mi][ni], 0, 0, 0);
    }

  __hip_bfloat16* op = o + (size_t)(nw * 256 + b) * 512 + h * 64;
#pragma unroll
  for (int mi = 0; mi < 4; ++mi)
#pragma unroll
    for (int ni = 0; ni < 4; ++ni) {
      int col = ni * 16 + lrow;
#pragma unroll
      for (int j = 0; j < 4; ++j) {
        int row = mi * 16 + lhi * 4 + j;
        op[(size_t)row * 2048 + col] = __float2bfloat16(acc[mi][ni][j]);
      }
    }
}

// -------- residual + LayerNorm on bf16 master (wave per row of 512) -------
// xb (bf16 master) <- LN(xb + f); if LAST also write fp32 row to xout.
template<bool LAST>
__global__ __launch_bounds__(256) void ln_res_b(
    __hip_bfloat16* __restrict__ xb, const __hip_bfloat16* __restrict__ f,
    const float* __restrict__ g, const float* __restrict__ be,
    float* __restrict__ xout) {
  const int w = threadIdx.x >> 6, l = threadIdx.x & 63;
  const size_t row = (size_t)blockIdx.x * 4 + w;
  const int c = l * 8;
  union { uint4 u; __hip_bfloat16 e[8]; } xa, fa;
  xa.u = *(const uint4*)(xb + row * 512 + c);
  fa.u = *(const uint4*)(f + row * 512 + c);
  float v[8];
#pragma unroll
  for (int j = 0; j < 8; ++j)
    v[j] = __bfloat162float(xa.e[j]) + __bfloat162float(fa.e[j]);
  float sum = 0.f, sq = 0.f;
#pragma unroll
  for (int j = 0; j < 8; ++j) { sum += v[j]; sq += v[j] * v[j]; }
#pragma unroll
  for (int m = 1; m < 64; m <<= 1) {
    sum += __shfl_xor(sum, m);
    sq += __shfl_xor(sq, m);
  }
  float mean = sum * (1.f / 512.f);
  float var = sq * (1.f / 512.f) - mean * mean;
  float rs = rsqrtf(var + 1e-5f);
  float4 g0 = *(const float4*)(g + c);
  float4 g1v = *(const float4*)(g + c + 4);
  float4 e0 = *(const float4*)(be + c);
  float4 e1 = *(const float4*)(be + c + 4);
  float gg[8] = {g0.x, g0.y, g0.z, g0.w, g1v.x, g1v.y, g1v.z, g1v.w};
  float ee[8] = {e0.x, e0.y, e0.z, e0.w, e1.x, e1.y, e1.z, e1.w};
  float y[8];
  union { uint4 u; __hip_bfloat16 e[8]; } hb;
#pragma unroll
  for (int j = 0; j < 8; ++j) {
    y[j] = (v[j] - mean) * rs * gg[j] + ee[j];
    hb.e[j] = __float2bfloat16(y[j]);
  }
  *(uint4*)(xb + row * 512 + c) = hb.u;
  if (LAST) {
    float4 o0 = {y[0], y[1], y[2], y[3]};
    float4 o1 = {y[4], y[5], y[6], y[7]};
    *(float4*)(xout + row * 512 + c) = o0;
    *(float4*)(xout + row * 512 + c + 4) = o1;
  }
}

// ---------------- setup / conversion kernels ------------------------------
__global__ void convq(const float* __restrict__ wq, __hip_bfloat16* __restrict__ o) {
  int i = blockIdx.x * 256 + threadIdx.x;  // over 6*1536*512/4 exactly
  float4 v = ((const float4*)wq)[i];
  int e = i * 4;
  float sc = (((e >> 9) % 1536) < 512) ? 0.125f : 1.f;
  __hip_bfloat16 hb[4] = {__float2bfloat16(v.x * sc), __float2bfloat16(v.y * sc),
                          __float2bfloat16(v.z * sc), __float2bfloat16(v.w * sc)};
  ((uint2*)o)[i] = *(uint2*)hb;
}

__global__ void convw(const float* __restrict__ s, __hip_bfloat16* __restrict__ o) {
  int i = blockIdx.x * 256 + threadIdx.x;  // exact grids only
  float4 v = ((const float4*)s)[i];
  __hip_bfloat16 hb[4] = {__float2bfloat16(v.x), __float2bfloat16(v.y),
                          __float2bfloat16(v.z), __float2bfloat16(v.w)};
  ((uint2*)o)[i] = *(uint2*)hb;
}

__global__ void scaleb(const float* __restrict__ b, float* __restrict__ o) {
  int i = blockIdx.x * 256 + threadIdx.x;  // over 9216 exactly
  o[i] = b[i] * (((i % 1536) < 512) ? 0.125f : 1.f);
}

// ---------------- launch ---------------------------------------------------
extern "C" void kernel_launch(void* const* d_in, const int* in_sizes, int n_in,
                              void* d_out, int out_size, void* d_ws, size_t ws_size,
                              hipStream_t stream) {
  const float* src  = (const float*)d_in[0];
  const float* Wqkv = (const float*)d_in[1];
  const float* bqkv = (const float*)d_in[2];
  const float* Wo   = (const float*)d_in[3];
  const float* bo   = (const float*)d_in[4];
  const float* W1   = (const float*)d_in[5];
  const float* bf1  = (const float*)d_in[6];
  const float* W2   = (const float*)d_in[7];
  const float* bf2  = (const float*)d_in[8];
  const float* g1   = (const float*)d_in[9];
  const float* be1  = (const float*)d_in[10];
  const float* g2   = (const float*)d_in[11];
  const float* be2  = (const float*)d_in[12];
  float* xout = (float*)d_out;  // fp32 output, written by the final LN

  char* ws = (char*)d_ws;
  size_t off = 0;
  auto alloc = [&](size_t bytes) {
    char* p = ws + off;
    off += (bytes + 255) & ~(size_t)255;
    return p;
  };

  const size_t wq_b = (size_t)L_ * D3 * D_ * 2;
  const size_t wo_b = (size_t)L_ * D_ * D_ * 2;
  const size_t w1_b = (size_t)L_ * DF * D_ * 2;
  const size_t w2_b = (size_t)L_ * D_ * DF * 2;
  const size_t xb_b = (size_t)NT * 512 * 2;  // bf16 residual master (all rows)
  auto al = [](size_t v) { return (v + 255) & ~(size_t)255; };
  const size_t persist =
      al(wq_b) + al(wo_b) + al(w1_b) + al(w2_b) + al(L_ * D3 * 4) + al(xb_b);

  // chunk of CT tokens needs: R CT*4096 + OB CT*1024 bytes
  int CT = NT;
  while (CT > 2048 && persist + (size_t)CT * 5120 + 65536 > ws_size) CT >>= 1;

  __hip_bfloat16* wqkvb = (__hip_bfloat16*)alloc(wq_b);
  __hip_bfloat16* wob   = (__hip_bfloat16*)alloc(wo_b);
  __hip_bfloat16* w1b   = (__hip_bfloat16*)alloc(w1_b);
  __hip_bfloat16* w2b   = (__hip_bfloat16*)alloc(w2_b);
  float*          bqs   = (float*)alloc((size_t)L_ * D3 * 4);
  __hip_bfloat16* xb    = (__hip_bfloat16*)alloc(xb_b);
  __hip_bfloat16* R     = (__hip_bfloat16*)alloc((size_t)CT * 2048 * 2);
  __hip_bfloat16* OB    = (__hip_bfloat16*)alloc((size_t)CT * 512 * 2);

  // init bf16 master from src; convert weights once
  convw<<<NT * 512 / 4 / 256, 256, 0, stream>>>(src, xb);
  convq<<<L_ * D3 * D_ / 4 / 256, 256, 0, stream>>>(Wqkv, wqkvb);
  convw<<<L_ * D_ * D_ / 4 / 256, 256, 0, stream>>>(Wo, wob);
  convw<<<L_ * DF * D_ / 4 / 256, 256, 0, stream>>>(W1, w1b);
  convw<<<L_ * D_ * DF / 4 / 256, 256, 0, stream>>>(W2, w2b);
  scaleb<<<L_ * D3 / 256, 256, 0, stream>>>(bqkv, bqs);

  const int nch = NT / CT;
  for (int c = 0; c < nch; ++c) {
    __hip_bfloat16* xm = xb + (size_t)c * CT * 512;
    float* xo = xout + (size_t)c * CT * 512;
    for (int l = 0; l < L_; ++l) {
      // qkv -> R[0 .. CT*1536)
      gemm256<512, 6, false><<<(CT / 256) * 6, 512, 0, stream>>>(
          xm, wqkvb + (size_t)l * D3 * D_, bqs + l * D3, R);
      attn_win<<<CT / 16, 128, 0, stream>>>(R, OB);
      // o-proj -> R[0 .. CT*512)
      gemm256<512, 2, false><<<(CT / 256) * 2, 512, 0, stream>>>(
          OB, wob + (size_t)l * D_ * D_, bo + l * D_, R);
      ln_res_b<false><<<CT / 4, 256, 0, stream>>>(xm, R, g1 + l * D_,
                                                  be1 + l * D_, xo);
      // ffn1 -> R full
      gemm256<512, 8, true><<<(CT / 256) * 8, 512, 0, stream>>>(
          xm, w1b + (size_t)l * DF * D_, bf1 + l * DF, R);
      // ffn2 -> OB
      gemm256<2048, 2, false><<<(CT / 256) * 2, 512, 0, stream>>>(
          R, w2b + (size_t)l * D_ * DF, bf2 + l * D_, OB);
      if (l == L_ - 1)
        ln_res_b<true><<<CT / 4, 256, 0, stream>>>(xm, OB, g2 + l * D_,
                                                   be2 + l * D_, xo);
      else
        ln_res_b<false><<<CT / 4, 256, 0, stream>>>(xm, OB, g2 + l * D_,
                                                    be2 + l * D_, xo);
    }
  }
}